// Round 2
// baseline (448.846 us; speedup 1.0000x reference)
//
#include <hip/hip_runtime.h>
#include <hip/hip_bf16.h>
#include <math.h>

#define BATCH   4
#define N_KP    1024
#define C_DIM   128
#define HW_     256
#define M_CELLS 1024
#define BIGV    10.0f
#define EPSV    1e-8f

__device__ inline float wsum(float v) {
#pragma unroll
    for (int off = 32; off > 0; off >>= 1) v += __shfl_xor(v, off, 64);
    return v;
}

// ---------------- K1: a = l2n(kp1_desc), row-major (B*N, C) ----------------
__global__ __launch_bounds__(64) void k_norm_a(const float* __restrict__ desc,
                                               float* __restrict__ a) {
    int row = blockIdx.x;            // b*N + n
    int l = threadIdx.x;             // 0..63
    const float2* src = (const float2*)(desc + (size_t)row * C_DIM);
    float2 v = src[l];
    float ss = wsum(v.x * v.x + v.y * v.y);
    float nrm = sqrtf(ss) + EPSV;
    float2* dst = (float2*)(a + (size_t)row * C_DIM);
    dst[l] = make_float2(v.x / nrm, v.y / nrm);
}

// Bilinear gather of 2 channels (c=2l, 2l+1) at (px,py) from desc2[b]
__device__ inline void bilin2(const float* __restrict__ desc2, int b,
                              float px, float py, int l, float* v) {
    float x = fminf(fmaxf(px, 0.f), (float)(HW_ - 1));
    float y = fminf(fmaxf(py, 0.f), (float)(HW_ - 1));
    float x0f = floorf(x), y0f = floorf(y);
    float wx = x - x0f, wy = y - y0f;
    int x0 = (int)x0f, y0 = (int)y0f;
    int x1 = min(x0 + 1, HW_ - 1), y1 = min(y0 + 1, HW_ - 1);
    float w00 = (1.f - wy) * (1.f - wx);
    float w01 = (1.f - wy) * wx;
    float w10 = wy * (1.f - wx);
    float w11 = wy * wx;
#pragma unroll
    for (int t = 0; t < 2; ++t) {
        int c = 2 * l + t;
        const float* p = desc2 + (size_t)(b * C_DIM + c) * HW_ * HW_;
        float v00 = p[y0 * HW_ + x0];
        float v01 = p[y0 * HW_ + x1];
        float v10 = p[y1 * HW_ + x0];
        float v11 = p[y1 * HW_ + x1];
        v[t] = v00 * w00 + v01 * w01 + v10 * w10 + v11 * w11;
    }
}

// ---------------- K2: wa (transposed + row-major stores) + pos ----------------
__global__ __launch_bounds__(64) void k_wa(const float* __restrict__ wkp,
                                           const float* __restrict__ desc2,
                                           const float* __restrict__ a,
                                           float* __restrict__ waT,   // (B, C, N)
                                           float* __restrict__ waR,   // (B, N, C)
                                           float* __restrict__ pos) {
    int row = blockIdx.x;            // b*N + n
    int b = row >> 10, n = row & 1023;
    int l = threadIdx.x;
    float px = wkp[(size_t)row * 2];
    float py = wkp[(size_t)row * 2 + 1];
    float vals[2];
    bilin2(desc2, b, px, py, l, vals);
    float ss = wsum(vals[0] * vals[0] + vals[1] * vals[1]);
    float nrm = sqrtf(ss) + EPSV;
    float w0 = vals[0] / nrm, w1 = vals[1] / nrm;
    waT[(size_t)(b * C_DIM + 2 * l) * N_KP + n]     = w0;
    waT[(size_t)(b * C_DIM + 2 * l + 1) * N_KP + n] = w1;
    ((float2*)(waR + (size_t)row * C_DIM))[l] = make_float2(w0, w1);
    const float2* ar = (const float2*)(a + (size_t)row * C_DIM);
    float2 av = ar[l];
    float d0 = av.x - w0, d1 = av.y - w1;
    float pp = wsum(d0 * d0 + d1 * d1);
    if (l == 0) pos[row] = sqrtf(pp);
}

// ---------------- K3: gd (transposed store) at grid centers ----------------
__global__ __launch_bounds__(64) void k_gd(const float* __restrict__ desc2,
                                           float* __restrict__ gdT) {  // (B, C, M)
    int idx = blockIdx.x;            // b*M + m
    int b = idx >> 10, m = idx & 1023;
    int l = threadIdx.x;
    float px = ((float)(m & 31) + 0.5f) * 8.0f;
    float py = ((float)(m >> 5) + 0.5f) * 8.0f;
    float vals[2];
    bilin2(desc2, b, px, py, l, vals);
    float ss = wsum(vals[0] * vals[0] + vals[1] * vals[1]);
    float nrm = sqrtf(ss) + EPSV;
    gdT[(size_t)(b * C_DIM + 2 * l) * M_CELLS + m]     = vals[0] / nrm;
    gdT[(size_t)(b * C_DIM + 2 * l + 1) * M_CELLS + m] = vals[1] / nrm;
}

// ---------------- K4: visibility + count ----------------
__global__ __launch_bounds__(256) void k_vis(const float* __restrict__ kp1,
                                             const float* __restrict__ homo,
                                             float* __restrict__ vis,
                                             float* __restrict__ acc) {
    int i = blockIdx.x * 256 + threadIdx.x;   // 0..4095
    int b = i >> 10;
    float x = kp1[(size_t)i * 2];
    float y = kp1[(size_t)i * 2 + 1];
    const float* h = homo + b * 9;
    float u = h[0] * x + h[1] * y + h[2];
    float v = h[3] * x + h[4] * y + h[5];
    float w = h[6] * x + h[7] * y + h[8];
    float wx_ = u / (w + EPSV);
    float wy_ = v / (w + EPSV);
    float viz = (wx_ >= 0.f && wx_ <= (float)(HW_ - 1) &&
                 wy_ >= 0.f && wy_ <= (float)(HW_ - 1)) ? 1.f : 0.f;
    vis[i] = viz;
    unsigned long long ball = __ballot(viz != 0.f);
    if ((threadIdx.x & 63) == 0) atomicAdd(&acc[2], (float)__popcll(ball));
}

// ---------------- K5a: neg matrix (B,N,M) with spatial mask ----------------
__global__ __launch_bounds__(256) void k_neg(const float* __restrict__ a,
                                             const float* __restrict__ gdT,
                                             const float* __restrict__ wkp,
                                             float* __restrict__ neg) {
    int b = blockIdx.z;
    int n0 = blockIdx.y * 8;
    int m = blockIdx.x * 256 + threadIdx.x;
    __shared__ float a_s[8 * C_DIM];
    __shared__ float w_s[8][2];
    for (int q = threadIdx.x; q < 8 * C_DIM; q += 256)
        a_s[q] = a[(size_t)(b * N_KP + n0) * C_DIM + q];
    if (threadIdx.x < 16)
        w_s[threadIdx.x >> 1][threadIdx.x & 1] =
            wkp[(size_t)(b * N_KP + n0) * 2 + threadIdx.x];
    __syncthreads();
    float acc[8] = {0.f, 0.f, 0.f, 0.f, 0.f, 0.f, 0.f, 0.f};
    const float* g = gdT + (size_t)b * C_DIM * M_CELLS + m;
#pragma unroll 4
    for (int c = 0; c < C_DIM; ++c) {
        float gv = g[(size_t)c * M_CELLS];
#pragma unroll
        for (int t = 0; t < 8; ++t) acc[t] += a_s[t * C_DIM + c] * gv;
    }
    float cgx = (float)(m & 31) * 8.0f + 4.0f;
    float cgy = (float)(m >> 5) * 8.0f + 4.0f;
#pragma unroll
    for (int t = 0; t < 8; ++t) {
        float d = sqrtf(fmaxf(2.f - 2.f * acc[t], 0.f) + EPSV);
        float dx = w_s[t][0] - cgx, dy = w_s[t][1] - cgy;
        if (dx * dx + dy * dy < 256.f) d = BIGV;   // sp < 2*GRID
        neg[(size_t)(b * N_KP + n0 + t) * M_CELLS + m] = d;
    }
}

// ---------------- K6a: d2m matrix (B,N,N) with spatial+diag mask ----------------
__global__ __launch_bounds__(256) void k_d2m(const float* __restrict__ waT,
                                             const float* __restrict__ waR,
                                             const float* __restrict__ wkp,
                                             float* __restrict__ d2m) {
    int b = blockIdx.z;
    int n0 = blockIdx.y * 8;
    int j = blockIdx.x * 256 + threadIdx.x;
    __shared__ float w_s2[8 * C_DIM];
    __shared__ float p_s[8][2];
    for (int q = threadIdx.x; q < 8 * C_DIM; q += 256)
        w_s2[q] = waR[(size_t)(b * N_KP + n0) * C_DIM + q];
    if (threadIdx.x < 16)
        p_s[threadIdx.x >> 1][threadIdx.x & 1] =
            wkp[(size_t)(b * N_KP + n0) * 2 + threadIdx.x];
    __syncthreads();
    float acc[8] = {0.f, 0.f, 0.f, 0.f, 0.f, 0.f, 0.f, 0.f};
    const float* g = waT + (size_t)b * C_DIM * N_KP + j;
#pragma unroll 4
    for (int c = 0; c < C_DIM; ++c) {
        float gv = g[(size_t)c * N_KP];
#pragma unroll
        for (int t = 0; t < 8; ++t) acc[t] += w_s2[t * C_DIM + c] * gv;
    }
    float wjx = wkp[(size_t)(b * N_KP + j) * 2];
    float wjy = wkp[(size_t)(b * N_KP + j) * 2 + 1];
#pragma unroll
    for (int t = 0; t < 8; ++t) {
        float d = sqrtf(fmaxf(2.f - 2.f * acc[t], 0.f) + EPSV);
        float dx = p_s[t][0] - wjx, dy = p_s[t][1] - wjy;
        if (dx * dx + dy * dy < 256.f || (n0 + t) == j) d = BIGV;
        d2m[(size_t)(b * N_KP + n0 + t) * N_KP + j] = d;
    }
}

// ---------------- K5b: FOS — top-8 smallest neg per row, relu sum ----------------
__global__ __launch_bounds__(64) void k_fos(const float* __restrict__ neg,
                                            const float* __restrict__ pos,
                                            const float* __restrict__ vis,
                                            float* __restrict__ acc) {
    int row = blockIdx.x;
    int l = threadIdx.x;
    const float* nr = neg + (size_t)row * M_CELLS;
    float bv[8]; int bi[8];
#pragma unroll
    for (int k = 0; k < 8; ++k) { bv[k] = 1e30f; bi[k] = 0x7fffffff; }
    for (int k = 0; k < 16; ++k) {
        int m = k * 64 + l;
        float v = nr[m];
        if (v < bv[7] || (v == bv[7] && m < bi[7])) {
            bv[7] = v; bi[7] = m;
#pragma unroll
            for (int t = 7; t > 0; --t) {
                if (bv[t] < bv[t - 1] || (bv[t] == bv[t - 1] && bi[t] < bi[t - 1])) {
                    float tv = bv[t]; bv[t] = bv[t - 1]; bv[t - 1] = tv;
                    int ti = bi[t]; bi[t] = bi[t - 1]; bi[t - 1] = ti;
                }
            }
        }
    }
    float p = pos[row];
    float s = 0.f;
#pragma unroll
    for (int r = 0; r < 8; ++r) {
        float v = bv[0]; int j = bi[0];
#pragma unroll
        for (int off = 1; off < 64; off <<= 1) {
            float ov = __shfl_xor(v, off, 64);
            int oj = __shfl_xor(j, off, 64);
            if (ov < v || (ov == v && oj < j)) { v = ov; j = oj; }
        }
        s += fmaxf(p - v + 1.0f, 0.f);
        if (j == bi[0]) {   // this lane owned the winner: pop head
#pragma unroll
            for (int t = 0; t < 7; ++t) { bv[t] = bv[t + 1]; bi[t] = bi[t + 1]; }
            bv[7] = 1e30f; bi[7] = 0x7fffffff;
        }
    }
    if (l == 0) atomicAdd(&acc[0], s * vis[row]);
}

// ---------------- K6b: SOS — top-8 smallest d2m + on-the-fly d1 gather ----------------
__global__ __launch_bounds__(64) void k_sos(const float* __restrict__ d2m,
                                            const float* __restrict__ a,
                                            const float* __restrict__ vis,
                                            float* __restrict__ acc) {
    int row = blockIdx.x;
    int b = row >> 10;
    int l = threadIdx.x;
    const float* dr = d2m + (size_t)row * N_KP;
    float bv[8]; int bi[8];
#pragma unroll
    for (int k = 0; k < 8; ++k) { bv[k] = 1e30f; bi[k] = 0x7fffffff; }
    for (int k = 0; k < 16; ++k) {
        int m = k * 64 + l;
        float v = dr[m];
        if (v < bv[7] || (v == bv[7] && m < bi[7])) {
            bv[7] = v; bi[7] = m;
#pragma unroll
            for (int t = 7; t > 0; --t) {
                if (bv[t] < bv[t - 1] || (bv[t] == bv[t - 1] && bi[t] < bi[t - 1])) {
                    float tv = bv[t]; bv[t] = bv[t - 1]; bv[t - 1] = tv;
                    int ti = bi[t]; bi[t] = bi[t - 1]; bi[t - 1] = ti;
                }
            }
        }
    }
    float sv[8]; int sj[8];
#pragma unroll
    for (int r = 0; r < 8; ++r) {
        float v = bv[0]; int j = bi[0];
#pragma unroll
        for (int off = 1; off < 64; off <<= 1) {
            float ov = __shfl_xor(v, off, 64);
            int oj = __shfl_xor(j, off, 64);
            if (ov < v || (ov == v && oj < j)) { v = ov; j = oj; }
        }
        sv[r] = v; sj[r] = j;
        if (j == bi[0]) {
#pragma unroll
            for (int t = 0; t < 7; ++t) { bv[t] = bv[t + 1]; bi[t] = bi[t + 1]; }
            bv[7] = 1e30f; bi[7] = 0x7fffffff;
        }
    }
    const float2* an = (const float2*)(a + (size_t)row * C_DIM);
    float2 av = an[l];
    float ss = 0.f;
#pragma unroll
    for (int r = 0; r < 8; ++r) {
        const float2* aj = (const float2*)(a + (size_t)(b * N_KP + sj[r]) * C_DIM);
        float2 jv = aj[l];
        float dot = wsum(av.x * jv.x + av.y * jv.y);
        float d1 = sqrtf(fmaxf(2.f - 2.f * dot, 0.f) + EPSV);
        float okv = (sv[r] < 5.0f) ? 1.f : 0.f;   // d2s < 0.5*BIG
        float diff = (d1 - sv[r]) * okv;
        ss += diff * diff;
    }
    float sos_i = sqrtf(ss + EPSV);
    if (l == 0) atomicAdd(&acc[1], sos_i * vis[row]);
}

// ---------------- K7: finalize ----------------
__global__ void k_fin(const float* __restrict__ acc, float* __restrict__ out) {
    float cnt = fmaxf(acc[2], 1.0f);
    float fos = acc[0] / (cnt * 8.0f);
    float sos = acc[1] / cnt;
    out[0] = fos + sos;
}

extern "C" void kernel_launch(void* const* d_in, const int* in_sizes, int n_in,
                              void* d_out, int out_size, void* d_ws, size_t ws_size,
                              hipStream_t stream) {
    (void)in_sizes; (void)n_in; (void)out_size; (void)ws_size;
    const float* kp1   = (const float*)d_in[0];
    const float* wkp   = (const float*)d_in[1];
    const float* kdesc = (const float*)d_in[2];
    const float* desc2 = (const float*)d_in[3];
    const float* homo  = (const float*)d_in[4];

    float* ws  = (float*)d_ws;
    float* acc = ws;                                   // [0]=fos [1]=sos [2]=cnt
    float* a   = ws + 16;                              // (B,N,C)
    float* waT = a + (size_t)BATCH * N_KP * C_DIM;     // (B,C,N)
    float* waR = waT + (size_t)BATCH * C_DIM * N_KP;   // (B,N,C)
    float* gdT = waR + (size_t)BATCH * N_KP * C_DIM;   // (B,C,M)
    float* pos = gdT + (size_t)BATCH * C_DIM * M_CELLS;
    float* vis = pos + BATCH * N_KP;
    float* mat = vis + BATCH * N_KP;                   // 16 MB, reused neg -> d2m

    hipMemsetAsync(acc, 0, 16 * sizeof(float), stream);
    k_norm_a<<<BATCH * N_KP, 64, 0, stream>>>(kdesc, a);
    k_wa<<<BATCH * N_KP, 64, 0, stream>>>(wkp, desc2, a, waT, waR, pos);
    k_gd<<<BATCH * M_CELLS, 64, 0, stream>>>(desc2, gdT);
    k_vis<<<16, 256, 0, stream>>>(kp1, homo, vis, acc);
    k_neg<<<dim3(M_CELLS / 256, N_KP / 8, BATCH), 256, 0, stream>>>(a, gdT, wkp, mat);
    k_fos<<<BATCH * N_KP, 64, 0, stream>>>(mat, pos, vis, acc);
    k_d2m<<<dim3(N_KP / 256, N_KP / 8, BATCH), 256, 0, stream>>>(waT, waR, wkp, mat);
    k_sos<<<BATCH * N_KP, 64, 0, stream>>>(mat, a, vis, acc);
    k_fin<<<1, 1, 0, stream>>>(acc, (float*)d_out);
}

// Round 3
// 401.067 us; speedup vs baseline: 1.1191x; 1.1191x over previous
//
#include <hip/hip_runtime.h>
#include <hip/hip_bf16.h>
#include <math.h>

#define BATCH   4
#define N_KP    1024
#define C_DIM   128
#define HW_     256
#define M_CELLS 1024
#define BIGV    10.0f
#define EPSV    1e-8f

__device__ inline float wsum(float v) {
#pragma unroll
    for (int off = 32; off > 0; off >>= 1) v += __shfl_xor(v, off, 64);
    return v;
}

// branchless insert of x into ascending sorted-8 (keep 8 smallest), values only
__device__ inline void ins8(float s[8], float x) {
    s[7] = fminf(s[7], x);
#pragma unroll
    for (int t = 7; t >= 1; --t) {
        float lo = fminf(s[t - 1], s[t]);
        float hi = fmaxf(s[t - 1], s[t]);
        s[t - 1] = lo; s[t] = hi;
    }
}

#define CE(a, b) { float _lo = fminf(a, b), _hi = fmaxf(a, b); a = _lo; b = _hi; }

// cross-lane merge: every lane has ascending sorted-8; after 6 bitonic stages
// all 64 lanes hold the identical global top-8 (ascending)
__device__ inline void merge64(float s[8]) {
#pragma unroll
    for (int d = 1; d < 64; d <<= 1) {
        float p[8];
#pragma unroll
        for (int i = 0; i < 8; ++i) p[i] = __shfl_xor(s[i], d, 64);
        float m[8];
#pragma unroll
        for (int i = 0; i < 8; ++i) m[i] = fminf(s[i], p[7 - i]);
        CE(m[0], m[4]); CE(m[1], m[5]); CE(m[2], m[6]); CE(m[3], m[7]);
        CE(m[0], m[2]); CE(m[1], m[3]); CE(m[4], m[6]); CE(m[5], m[7]);
        CE(m[0], m[1]); CE(m[2], m[3]); CE(m[4], m[5]); CE(m[6], m[7]);
#pragma unroll
        for (int i = 0; i < 8; ++i) s[i] = m[i];
    }
}

// ---------------- K1: a = l2n(kp1_desc), row-major (B*N, C) ----------------
__global__ __launch_bounds__(64) void k_norm_a(const float* __restrict__ desc,
                                               float* __restrict__ a) {
    int row = blockIdx.x;
    int l = threadIdx.x;
    const float2* src = (const float2*)(desc + (size_t)row * C_DIM);
    float2 v = src[l];
    float ss = wsum(v.x * v.x + v.y * v.y);
    float nrm = sqrtf(ss) + EPSV;
    float2* dst = (float2*)(a + (size_t)row * C_DIM);
    dst[l] = make_float2(v.x / nrm, v.y / nrm);
}

// Bilinear gather of 2 channels (c=2l, 2l+1) at (px,py) from desc2[b]
__device__ inline void bilin2(const float* __restrict__ desc2, int b,
                              float px, float py, int l, float* v) {
    float x = fminf(fmaxf(px, 0.f), (float)(HW_ - 1));
    float y = fminf(fmaxf(py, 0.f), (float)(HW_ - 1));
    float x0f = floorf(x), y0f = floorf(y);
    float wx = x - x0f, wy = y - y0f;
    int x0 = (int)x0f, y0 = (int)y0f;
    int x1 = min(x0 + 1, HW_ - 1), y1 = min(y0 + 1, HW_ - 1);
    float w00 = (1.f - wy) * (1.f - wx);
    float w01 = (1.f - wy) * wx;
    float w10 = wy * (1.f - wx);
    float w11 = wy * wx;
#pragma unroll
    for (int t = 0; t < 2; ++t) {
        int c = 2 * l + t;
        const float* p = desc2 + (size_t)(b * C_DIM + c) * HW_ * HW_;
        float v00 = p[y0 * HW_ + x0];
        float v01 = p[y0 * HW_ + x1];
        float v10 = p[y1 * HW_ + x0];
        float v11 = p[y1 * HW_ + x1];
        v[t] = v00 * w00 + v01 * w01 + v10 * w10 + v11 * w11;
    }
}

// ---------------- K2: wa (transposed + row-major stores) + pos ----------------
__global__ __launch_bounds__(64) void k_wa(const float* __restrict__ wkp,
                                           const float* __restrict__ desc2,
                                           const float* __restrict__ a,
                                           float* __restrict__ waT,   // (B, C, N)
                                           float* __restrict__ waR,   // (B, N, C)
                                           float* __restrict__ pos) {
    int row = blockIdx.x;
    int b = row >> 10, n = row & 1023;
    int l = threadIdx.x;
    float px = wkp[(size_t)row * 2];
    float py = wkp[(size_t)row * 2 + 1];
    float vals[2];
    bilin2(desc2, b, px, py, l, vals);
    float ss = wsum(vals[0] * vals[0] + vals[1] * vals[1]);
    float nrm = sqrtf(ss) + EPSV;
    float w0 = vals[0] / nrm, w1 = vals[1] / nrm;
    waT[(size_t)(b * C_DIM + 2 * l) * N_KP + n]     = w0;
    waT[(size_t)(b * C_DIM + 2 * l + 1) * N_KP + n] = w1;
    ((float2*)(waR + (size_t)row * C_DIM))[l] = make_float2(w0, w1);
    const float2* ar = (const float2*)(a + (size_t)row * C_DIM);
    float2 av = ar[l];
    float d0 = av.x - w0, d1 = av.y - w1;
    float pp = wsum(d0 * d0 + d1 * d1);
    if (l == 0) pos[row] = sqrtf(pp);
}

// ---------------- K3: gd (transposed store) at grid centers ----------------
__global__ __launch_bounds__(64) void k_gd(const float* __restrict__ desc2,
                                           float* __restrict__ gdT) {  // (B, C, M)
    int idx = blockIdx.x;
    int b = idx >> 10, m = idx & 1023;
    int l = threadIdx.x;
    float px = ((float)(m & 31) + 0.5f) * 8.0f;
    float py = ((float)(m >> 5) + 0.5f) * 8.0f;
    float vals[2];
    bilin2(desc2, b, px, py, l, vals);
    float ss = wsum(vals[0] * vals[0] + vals[1] * vals[1]);
    float nrm = sqrtf(ss) + EPSV;
    gdT[(size_t)(b * C_DIM + 2 * l) * M_CELLS + m]     = vals[0] / nrm;
    gdT[(size_t)(b * C_DIM + 2 * l + 1) * M_CELLS + m] = vals[1] / nrm;
}

// ---------------- K4: visibility + count ----------------
__global__ __launch_bounds__(256) void k_vis(const float* __restrict__ kp1,
                                             const float* __restrict__ homo,
                                             float* __restrict__ vis,
                                             float* __restrict__ acc) {
    int i = blockIdx.x * 256 + threadIdx.x;
    int b = i >> 10;
    float x = kp1[(size_t)i * 2];
    float y = kp1[(size_t)i * 2 + 1];
    const float* h = homo + b * 9;
    float u = h[0] * x + h[1] * y + h[2];
    float v = h[3] * x + h[4] * y + h[5];
    float w = h[6] * x + h[7] * y + h[8];
    float wx_ = u / (w + EPSV);
    float wy_ = v / (w + EPSV);
    float viz = (wx_ >= 0.f && wx_ <= (float)(HW_ - 1) &&
                 wy_ >= 0.f && wy_ <= (float)(HW_ - 1)) ? 1.f : 0.f;
    vis[i] = viz;
    unsigned long long ball = __ballot(viz != 0.f);
    if ((threadIdx.x & 63) == 0) atomicAdd(&acc[2], (float)__popcll(ball));
}

// ---------------- K5a: neg matrix (B,N,M); 8 rows x 2 cols per thread ----------------
__global__ __launch_bounds__(256) void k_neg(const float* __restrict__ a,
                                             const float* __restrict__ gdT,
                                             const float* __restrict__ wkp,
                                             float* __restrict__ neg) {
    int b = blockIdx.z;
    int n0 = blockIdx.y * 8;
    int jj = blockIdx.x * 256 + threadIdx.x;     // col-pair index: cols 2jj, 2jj+1
    const float* A = a + (size_t)(b * N_KP + n0) * C_DIM;   // 8x128, block-uniform
    const float2* G = (const float2*)(gdT + (size_t)b * C_DIM * M_CELLS);
    float2 s[8];
#pragma unroll
    for (int t = 0; t < 8; ++t) s[t] = make_float2(0.f, 0.f);
#pragma unroll 4
    for (int c4 = 0; c4 < C_DIM / 4; ++c4) {
        float2 g0 = G[(size_t)(4 * c4 + 0) * (M_CELLS / 2) + jj];
        float2 g1 = G[(size_t)(4 * c4 + 1) * (M_CELLS / 2) + jj];
        float2 g2 = G[(size_t)(4 * c4 + 2) * (M_CELLS / 2) + jj];
        float2 g3 = G[(size_t)(4 * c4 + 3) * (M_CELLS / 2) + jj];
#pragma unroll
        for (int t = 0; t < 8; ++t) {
            float a0 = A[t * C_DIM + 4 * c4 + 0];
            float a1 = A[t * C_DIM + 4 * c4 + 1];
            float a2 = A[t * C_DIM + 4 * c4 + 2];
            float a3 = A[t * C_DIM + 4 * c4 + 3];
            s[t].x += a0 * g0.x + a1 * g1.x + a2 * g2.x + a3 * g3.x;
            s[t].y += a0 * g0.y + a1 * g1.y + a2 * g2.y + a3 * g3.y;
        }
    }
    int j0 = 2 * jj, j1 = 2 * jj + 1;
    float cgx0 = (float)(j0 & 31) * 8.0f + 4.0f, cgy0 = (float)((j0 & 1023) >> 5) * 8.0f + 4.0f;
    float cgx1 = (float)(j1 & 31) * 8.0f + 4.0f, cgy1 = (float)((j1 & 1023) >> 5) * 8.0f + 4.0f;
#pragma unroll
    for (int t = 0; t < 8; ++t) {
        float wx = wkp[(size_t)(b * N_KP + n0 + t) * 2];
        float wy = wkp[(size_t)(b * N_KP + n0 + t) * 2 + 1];
        float dx0 = wx - cgx0, dy0 = wy - cgy0;
        float dx1 = wx - cgx1, dy1 = wy - cgy1;
        float d0 = sqrtf(fmaxf(2.f - 2.f * s[t].x, 0.f) + EPSV);
        float d1 = sqrtf(fmaxf(2.f - 2.f * s[t].y, 0.f) + EPSV);
        if (dx0 * dx0 + dy0 * dy0 < 256.f) d0 = BIGV;
        if (dx1 * dx1 + dy1 * dy1 < 256.f) d1 = BIGV;
        ((float2*)(neg + (size_t)(b * N_KP + n0 + t) * M_CELLS))[jj & 511] = make_float2(d0, d1);
    }
}

// ---------------- K6a: d2m matrix (B,N,N); 8 rows x 2 cols per thread ----------------
__global__ __launch_bounds__(256) void k_d2m(const float* __restrict__ waT,
                                             const float* __restrict__ waR,
                                             const float* __restrict__ wkp,
                                             float* __restrict__ d2m) {
    int b = blockIdx.z;
    int n0 = blockIdx.y * 8;
    int jj = blockIdx.x * 256 + threadIdx.x;     // col-pair index: cols 2jj, 2jj+1
    const float* A = waR + (size_t)(b * N_KP + n0) * C_DIM;
    const float2* G = (const float2*)(waT + (size_t)b * C_DIM * N_KP);
    float2 s[8];
#pragma unroll
    for (int t = 0; t < 8; ++t) s[t] = make_float2(0.f, 0.f);
#pragma unroll 4
    for (int c4 = 0; c4 < C_DIM / 4; ++c4) {
        float2 g0 = G[(size_t)(4 * c4 + 0) * (N_KP / 2) + jj];
        float2 g1 = G[(size_t)(4 * c4 + 1) * (N_KP / 2) + jj];
        float2 g2 = G[(size_t)(4 * c4 + 2) * (N_KP / 2) + jj];
        float2 g3 = G[(size_t)(4 * c4 + 3) * (N_KP / 2) + jj];
#pragma unroll
        for (int t = 0; t < 8; ++t) {
            float a0 = A[t * C_DIM + 4 * c4 + 0];
            float a1 = A[t * C_DIM + 4 * c4 + 1];
            float a2 = A[t * C_DIM + 4 * c4 + 2];
            float a3 = A[t * C_DIM + 4 * c4 + 3];
            s[t].x += a0 * g0.x + a1 * g1.x + a2 * g2.x + a3 * g3.x;
            s[t].y += a0 * g0.y + a1 * g1.y + a2 * g2.y + a3 * g3.y;
        }
    }
    int j0 = 2 * (jj & 511), j1 = j0 + 1;
    float4 wj = ((const float4*)(wkp + (size_t)b * N_KP * 2))[jj & 511];  // x0,y0,x1,y1
#pragma unroll
    for (int t = 0; t < 8; ++t) {
        float wx = wkp[(size_t)(b * N_KP + n0 + t) * 2];
        float wy = wkp[(size_t)(b * N_KP + n0 + t) * 2 + 1];
        float dx0 = wx - wj.x, dy0 = wy - wj.y;
        float dx1 = wx - wj.z, dy1 = wy - wj.w;
        float d0 = sqrtf(fmaxf(2.f - 2.f * s[t].x, 0.f) + EPSV);
        float d1 = sqrtf(fmaxf(2.f - 2.f * s[t].y, 0.f) + EPSV);
        if (dx0 * dx0 + dy0 * dy0 < 256.f || (n0 + t) == j0) d0 = BIGV;
        if (dx1 * dx1 + dy1 * dy1 < 256.f || (n0 + t) == j1) d1 = BIGV;
        ((float2*)(d2m + (size_t)(b * N_KP + n0 + t) * N_KP))[jj & 511] = make_float2(d0, d1);
    }
}

// ---------------- K5b: FOS — branchless top-8 values + relu sum ----------------
__global__ __launch_bounds__(256) void k_fos(const float* __restrict__ neg,
                                             const float* __restrict__ pos,
                                             const float* __restrict__ vis,
                                             float* __restrict__ acc) {
    int row = blockIdx.x * 4 + (threadIdx.x >> 6);
    int l = threadIdx.x & 63;
    const float4* nr = (const float4*)(neg + (size_t)row * M_CELLS);
    float s[8];
#pragma unroll
    for (int k = 0; k < 8; ++k) s[k] = 1e30f;
    float4 v0 = nr[l], v1 = nr[l + 64], v2 = nr[l + 128], v3 = nr[l + 192];
    ins8(s, v0.x); ins8(s, v0.y); ins8(s, v0.z); ins8(s, v0.w);
    ins8(s, v1.x); ins8(s, v1.y); ins8(s, v1.z); ins8(s, v1.w);
    ins8(s, v2.x); ins8(s, v2.y); ins8(s, v2.z); ins8(s, v2.w);
    ins8(s, v3.x); ins8(s, v3.y); ins8(s, v3.z); ins8(s, v3.w);
    merge64(s);
    if (l == 0) {
        float p = pos[row];
        float sum = 0.f;
#pragma unroll
        for (int r = 0; r < 8; ++r) sum += fmaxf(p - s[r] + 1.0f, 0.f);
        atomicAdd(&acc[0], sum * vis[row]);
    }
}

// ---------------- K6b: SOS — packed-key top-8 + d1 gather ----------------
__device__ inline float packkey(float v, int j) {
    return __uint_as_float((__float_as_uint(v) & 0xFFFFFC00u) | (unsigned)j);
}

__global__ __launch_bounds__(256) void k_sos(const float* __restrict__ d2m,
                                             const float* __restrict__ a,
                                             const float* __restrict__ vis,
                                             float* __restrict__ acc) {
    int row = blockIdx.x * 4 + (threadIdx.x >> 6);
    int b = row >> 10;
    int l = threadIdx.x & 63;
    const float4* dr = (const float4*)(d2m + (size_t)row * N_KP);
    float s[8];
#pragma unroll
    for (int k = 0; k < 8; ++k) s[k] = 1e30f;
#pragma unroll
    for (int k = 0; k < 4; ++k) {
        float4 v = dr[l + 64 * k];
        int j = 4 * (l + 64 * k);
        ins8(s, packkey(v.x, j));
        ins8(s, packkey(v.y, j + 1));
        ins8(s, packkey(v.z, j + 2));
        ins8(s, packkey(v.w, j + 3));
    }
    merge64(s);
    // every lane now holds the identical top-8 keys
    const float2* an = (const float2*)(a + (size_t)row * C_DIM);
    float2 av = an[l];
    float ss = 0.f;
#pragma unroll
    for (int r = 0; r < 8; ++r) {
        unsigned uk = __float_as_uint(s[r]);
        int j = (int)(uk & 1023u);
        float d2s = __uint_as_float(uk & 0xFFFFFC00u);
        const float2* aj = (const float2*)(a + (size_t)(b * N_KP + j) * C_DIM);
        float2 jv = aj[l];
        float dot = wsum(av.x * jv.x + av.y * jv.y);
        float d1 = sqrtf(fmaxf(2.f - 2.f * dot, 0.f) + EPSV);
        float okv = (d2s < 5.0f) ? 1.f : 0.f;
        float diff = (d1 - d2s) * okv;
        ss += diff * diff;
    }
    if (l == 0) atomicAdd(&acc[1], sqrtf(ss + EPSV) * vis[row]);
}

// ---------------- K7: finalize ----------------
__global__ void k_fin(const float* __restrict__ acc, float* __restrict__ out) {
    float cnt = fmaxf(acc[2], 1.0f);
    float fos = acc[0] / (cnt * 8.0f);
    float sos = acc[1] / cnt;
    out[0] = fos + sos;
}

extern "C" void kernel_launch(void* const* d_in, const int* in_sizes, int n_in,
                              void* d_out, int out_size, void* d_ws, size_t ws_size,
                              hipStream_t stream) {
    (void)in_sizes; (void)n_in; (void)out_size; (void)ws_size;
    const float* kp1   = (const float*)d_in[0];
    const float* wkp   = (const float*)d_in[1];
    const float* kdesc = (const float*)d_in[2];
    const float* desc2 = (const float*)d_in[3];
    const float* homo  = (const float*)d_in[4];

    float* ws  = (float*)d_ws;
    float* acc = ws;                                   // [0]=fos [1]=sos [2]=cnt
    float* a   = ws + 16;                              // (B,N,C)
    float* waT = a + (size_t)BATCH * N_KP * C_DIM;     // (B,C,N)
    float* waR = waT + (size_t)BATCH * C_DIM * N_KP;   // (B,N,C)
    float* gdT = waR + (size_t)BATCH * N_KP * C_DIM;   // (B,C,M)
    float* pos = gdT + (size_t)BATCH * C_DIM * M_CELLS;
    float* vis = pos + BATCH * N_KP;
    float* mat = vis + BATCH * N_KP;                   // 16 MB, reused neg -> d2m

    hipMemsetAsync(acc, 0, 16 * sizeof(float), stream);
    k_norm_a<<<BATCH * N_KP, 64, 0, stream>>>(kdesc, a);
    k_wa<<<BATCH * N_KP, 64, 0, stream>>>(wkp, desc2, a, waT, waR, pos);
    k_gd<<<BATCH * M_CELLS, 64, 0, stream>>>(desc2, gdT);
    k_vis<<<16, 256, 0, stream>>>(kp1, homo, vis, acc);
    k_neg<<<dim3(M_CELLS / 512, N_KP / 8, BATCH), 256, 0, stream>>>(a, gdT, wkp, mat);
    k_fos<<<BATCH * N_KP / 4, 256, 0, stream>>>(mat, pos, vis, acc);
    k_d2m<<<dim3(N_KP / 512, N_KP / 8, BATCH), 256, 0, stream>>>(waT, waR, wkp, mat);
    k_sos<<<BATCH * N_KP / 4, 256, 0, stream>>>(mat, a, vis, acc);
    k_fin<<<1, 1, 0, stream>>>(acc, (float*)d_out);
}